// Round 1
// baseline (141.829 us; speedup 1.0000x reference)
//
#include <hip/hip_runtime.h>
#include <hip/hip_bf16.h>
#include <stdint.h>

// FourierAttention = irfft(rfft(x)) @ W^T + b  ==  x @ W^T + b  (FFT roundtrip is identity).
// Strategy: cvt x,W -> bf16 in d_ws, then m97-style 128x128 bf16 MFMA GEMM (NT layout).

typedef __bf16 bf16_t;
typedef __bf16 bf16x8 __attribute__((ext_vector_type(8)));
typedef float f32x4 __attribute__((ext_vector_type(4)));

typedef __attribute__((address_space(1))) const void gvoid;
typedef __attribute__((address_space(3))) void svoid;

// ---------------- fp32 -> bf16 conversion, 8 elems/thread ----------------
__global__ __launch_bounds__(256) void cvt_f32_bf16_kernel(const float* __restrict__ in,
                                                           bf16_t* __restrict__ out, int n8) {
  int i = blockIdx.x * 256 + threadIdx.x;
  if (i >= n8) return;
  const f32x4* p = (const f32x4*)in + (size_t)i * 2;
  f32x4 v0 = p[0];
  f32x4 v1 = p[1];
  bf16x8 o;
  o[0] = (bf16_t)v0[0]; o[1] = (bf16_t)v0[1]; o[2] = (bf16_t)v0[2]; o[3] = (bf16_t)v0[3];
  o[4] = (bf16_t)v1[0]; o[5] = (bf16_t)v1[1]; o[6] = (bf16_t)v1[2]; o[7] = (bf16_t)v1[3];
  *(bf16x8*)(out + (size_t)i * 8) = o;
}

// ---------------- m97-style bf16 NT-GEMM: C[M][N] = A[M][K] * B[N][K]^T + bias ----------------
// 128x128 tile, BK=32, 256 threads (4 waves in 2x2), 16x16x32 MFMA, 4x4 frags/wave.
__global__ __launch_bounds__(256) void gemm_bt_bias_kernel(
    const bf16_t* __restrict__ A, const bf16_t* __restrict__ B,
    const float* __restrict__ bias, float* __restrict__ C,
    int M, int N, int K) {
  __shared__ __align__(16) bf16_t As[128 * 32];  // 8 KB
  __shared__ __align__(16) bf16_t Bs[128 * 32];  // 8 KB

  // Bijective XCD-aware swizzle (nwg % 8 == 0 here): each XCD gets a contiguous
  // chunk of row-tiles -> A-tile reuse across the 8 N-tiles stays in that XCD's L2.
  int nwg = gridDim.x;
  int bid = blockIdx.x;
  int wg = bid;
  if ((nwg & 7) == 0) {
    int cpx = nwg >> 3;
    wg = (bid & 7) * cpx + (bid >> 3);
  }
  int ntn = N >> 7;       // N / 128
  int tm = wg / ntn;
  int tn = wg % ntn;

  int tid = threadIdx.x;
  int wave = tid >> 6;
  int lane = tid & 63;
  int qr = lane & 15;     // fragment row (A) / col (B)
  int qg = lane >> 4;     // k-group (8 contiguous bf16)
  int wrow = (wave >> 1) << 6;  // 0 or 64
  int wcol = (wave & 1) << 6;   // 0 or 64

  // Staging: thread tid covers row tid>>2 (and +64), 16B chunk tid&3.
  // LDS dest offset = tid*16 B  -> linear in lane, as global_load_lds requires.
  const bf16_t* Ag = A + (size_t)(tm * 128 + (tid >> 2)) * K + (tid & 3) * 8;
  const bf16_t* Bg = B + (size_t)(tn * 128 + (tid >> 2)) * K + (tid & 3) * 8;
  bf16_t* Asw = As + tid * 8;
  bf16_t* Bsw = Bs + tid * 8;
  const size_t half = (size_t)64 * K;

  f32x4 acc[4][4] = {};

  for (int k0 = 0; k0 < K; k0 += 32) {
    __builtin_amdgcn_global_load_lds((gvoid*)(Ag + k0), (svoid*)(Asw), 16, 0, 0);
    __builtin_amdgcn_global_load_lds((gvoid*)(Ag + half + k0), (svoid*)(Asw + 2048), 16, 0, 0);
    __builtin_amdgcn_global_load_lds((gvoid*)(Bg + k0), (svoid*)(Bsw), 16, 0, 0);
    __builtin_amdgcn_global_load_lds((gvoid*)(Bg + half + k0), (svoid*)(Bsw + 2048), 16, 0, 0);
    __syncthreads();

    bf16x8 af[4], bfr[4];
#pragma unroll
    for (int m = 0; m < 4; ++m)
      af[m] = *(const bf16x8*)(As + (wrow + m * 16 + qr) * 32 + qg * 8);
#pragma unroll
    for (int n = 0; n < 4; ++n)
      bfr[n] = *(const bf16x8*)(Bs + (wcol + n * 16 + qr) * 32 + qg * 8);
#pragma unroll
    for (int m = 0; m < 4; ++m)
#pragma unroll
      for (int n = 0; n < 4; ++n)
        acc[m][n] = __builtin_amdgcn_mfma_f32_16x16x32_bf16(af[m], bfr[n], acc[m][n], 0, 0, 0);

    __syncthreads();
  }

  // Epilogue: C/D layout col = lane&15, row = (lane>>4)*4 + reg (verified m89/m91).
  int col0 = tn * 128 + wcol;
  float bv[4];
#pragma unroll
  for (int n = 0; n < 4; ++n) bv[n] = bias[col0 + n * 16 + qr];
  size_t rbase = (size_t)(tm * 128 + wrow + qg * 4);
#pragma unroll
  for (int m = 0; m < 4; ++m) {
#pragma unroll
    for (int r = 0; r < 4; ++r) {
      float* crow = C + (rbase + m * 16 + r) * N;
#pragma unroll
      for (int n = 0; n < 4; ++n)
        crow[col0 + n * 16 + qr] = acc[m][n][r] + bv[n];
    }
  }
}

// ---------------- safety-net fp32 GEMM (only if workspace too small) ----------------
__global__ __launch_bounds__(256) void naive_kernel(const float* __restrict__ x,
                                                    const float* __restrict__ W,
                                                    const float* __restrict__ b,
                                                    float* __restrict__ out,
                                                    int M, int N, int K) {
  long idx = (long)blockIdx.x * 256 + threadIdx.x;
  if (idx >= (long)M * N) return;
  int m = (int)(idx / N), n = (int)(idx % N);
  const float* xr = x + (size_t)m * K;
  const float* wr = W + (size_t)n * K;
  float s = 0.f;
  for (int k = 0; k < K; ++k) s += xr[k] * wr[k];
  out[idx] = s + b[n];
}

extern "C" void kernel_launch(void* const* d_in, const int* in_sizes, int n_in,
                              void* d_out, int out_size, void* d_ws, size_t ws_size,
                              hipStream_t stream) {
  const float* x = (const float*)d_in[0];   // [B,L,D] fp32
  const float* W = (const float*)d_in[1];   // [D,D] fp32 (out,in)
  const float* b = (const float*)d_in[2];   // [D] fp32
  float* out = (float*)d_out;

  int D = in_sizes[2];
  int M = in_sizes[0] / D;
  int N = D, K = D;

  size_t need = (size_t)(4u << 20) + (size_t)M * (size_t)K * sizeof(bf16_t);
  bool fast = (ws_size >= need) && (M % 128 == 0) && (N % 128 == 0) && (K % 32 == 0) &&
              (in_sizes[1] == N * K);

  if (fast) {
    bf16_t* Wb = (bf16_t*)d_ws;                          // 2 MB
    bf16_t* Xb = (bf16_t*)((char*)d_ws + (4u << 20));    // 64 MB
    int n8w = (N * K) / 8;
    hipLaunchKernelGGL(cvt_f32_bf16_kernel, dim3((n8w + 255) / 256), dim3(256), 0, stream,
                       W, Wb, n8w);
    int n8x = (int)(((size_t)M * K) / 8);
    hipLaunchKernelGGL(cvt_f32_bf16_kernel, dim3((n8x + 255) / 256), dim3(256), 0, stream,
                       x, Xb, n8x);
    int nwg = (M / 128) * (N / 128);
    hipLaunchKernelGGL(gemm_bt_bias_kernel, dim3(nwg), dim3(256), 0, stream,
                       Xb, Wb, b, out, M, N, K);
  } else {
    long total = (long)M * N;
    hipLaunchKernelGGL(naive_kernel, dim3((int)((total + 255) / 256)), dim3(256), 0, stream,
                       x, W, b, out, M, N, K);
  }
}

// Round 2
// 118.980 us; speedup vs baseline: 1.1920x; 1.1920x over previous
//
#include <hip/hip_runtime.h>
#include <hip/hip_bf16.h>
#include <stdint.h>

// FourierAttention = irfft(rfft(x)) @ W^T + b  ==  x @ W^T + b  (FFT roundtrip is identity).
// R2: cvt x,W -> bf16 in MFMA-fragment-tiled layout, then 256x256 8-phase GEMM
// (T3+T4 counted-vmcnt + T5 setprio, conflict-free linear LDS reads).

typedef __bf16 bf16_t;
typedef __bf16 bf16x8 __attribute__((ext_vector_type(8)));
typedef float f32x4 __attribute__((ext_vector_type(4)));

typedef __attribute__((address_space(1))) const void gvoid;
typedef __attribute__((address_space(3))) void svoid;

// ---------------- fp32 -> bf16 cvt into fragment-tiled layout ----------------
// out layout: subtile s = (r16_tile * (K/32) + k32_tile), each subtile 1KB =
// 64 lanes x 16B; lane = qg*16 + qr holds  src[row = r16*16+qr][k = kb*32+qg*8 .. +7].
__global__ __launch_bounds__(256) void cvt_frag_kernel(const float* __restrict__ in,
                                                       bf16_t* __restrict__ out,
                                                       int K, int ksh, long total8) {
  long tid = (long)blockIdx.x * 256 + threadIdx.x;
  if (tid >= total8) return;
  int lane = (int)(tid & 63);
  long s = tid >> 6;
  int kb = (int)(s & ((1 << ksh) - 1));
  long m16 = s >> ksh;
  long row = m16 * 16 + (lane & 15);
  int k0 = kb * 32 + (lane >> 4) * 8;
  const float* p = in + row * (long)K + k0;
  f32x4 v0 = *(const f32x4*)p;
  f32x4 v1 = *(const f32x4*)(p + 4);
  bf16x8 o;
  o[0] = (bf16_t)v0[0]; o[1] = (bf16_t)v0[1]; o[2] = (bf16_t)v0[2]; o[3] = (bf16_t)v0[3];
  o[4] = (bf16_t)v1[0]; o[5] = (bf16_t)v1[1]; o[6] = (bf16_t)v1[2]; o[7] = (bf16_t)v1[3];
  *(bf16x8*)(out + tid * 8) = o;
}

// ---------------- 256x256 8-phase bf16 GEMM ----------------
// A (frag-tiled) [M/16][K/32][1KB], B (frag-tiled) [N/16][K/32][1KB].
// 512 thr = 8 waves (2M x 4N); wave tile 128x64; BK=64; LDS 128KB (2 bufs x (A32K+B32K)).

__device__ __forceinline__ void stage_half(const bf16_t* __restrict__ base, int tile16,
                                           int kdiv32, int t, int kb, int isB, int buf,
                                           bf16_t* lds, int wid, int lane8) {
#pragma unroll
  for (int r = 0; r < 2; ++r) {
    int s = r * 8 + wid;  // local 16-row (or 16-col) subtile index, wave-uniform
    size_t gElem = ((((size_t)(tile16 + s)) * kdiv32 + (size_t)(t * 2 + kb)) << 9) + lane8;
    int dElem = buf * 32768 + isB * 16384 + (s * 2 + kb) * 512 + lane8;
    __builtin_amdgcn_global_load_lds((gvoid*)(base + gElem), (svoid*)(lds + dElem), 16, 0, 0);
  }
}

#define GATE6() asm volatile("s_waitcnt vmcnt(6)" ::: "memory")
#define BAR() __builtin_amdgcn_s_barrier()

__global__ __launch_bounds__(512, 2) void gemm8p_kernel(
    const bf16_t* __restrict__ A, const bf16_t* __restrict__ B,
    const float* __restrict__ bias, float* __restrict__ C,
    int M, int N, int K) {
  __shared__ __align__(16) bf16_t lds[65536];  // 128 KB

  const int kdiv32 = K >> 5;
  const int NT = K >> 6;  // K-tiles of 64; guaranteed even, >= 2 by host gate

  int nwg = gridDim.x;
  int bid = blockIdx.x;
  int wg = bid;
  if ((nwg & 7) == 0) wg = (bid & 7) * (nwg >> 3) + (bid >> 3);  // bijective XCD chunking
  int ntn = N >> 8;
  int tm = wg / ntn, tn = wg % ntn;

  int tid = threadIdx.x;
  int wid = tid >> 6, lane = tid & 63;
  int wm = wid >> 2, wn = wid & 3;  // 2 x 4 wave grid
  int qr = lane & 15, qg = lane >> 4;
  int lane8 = lane * 8;
  int wm8 = wm * 8;  // wave's first m-frag (0 or 8)
  int wn4 = wn * 4;  // wave's first n-frag
  int tm16 = tm * 16, tn16 = tn * 16;

  f32x4 acc[8][4] = {};
  bf16x8 aF[8], bF[2];

#define STAGE_A(t, kb, buf) stage_half(A, tm16, kdiv32, (t), (kb), 0, (buf), lds, wid, lane8)
#define STAGE_B(t, kb, buf) stage_half(B, tn16, kdiv32, (t), (kb), 1, (buf), lds, wid, lane8)
#define LDA_(mm, kb, buf) (*(const bf16x8*)(lds + (buf)*32768 + ((wm8 + (mm)) * 2 + (kb)) * 512 + lane8))
#define LDB_(nn, kb, buf) (*(const bf16x8*)(lds + (buf)*32768 + 16384 + ((wn4 + (nn)) * 2 + (kb)) * 512 + lane8))

  // Phase: ds-read frags -> issue one half-stage -> [gate] -> barrier -> setprio(1)
  // -> 16 MFMA -> setprio(0) -> barrier.  (8-phase template, counted vmcnt.)
#define PHASE(buf, kb, nh, LOADA, STMT_STAGE, DO_GATE)                                     \
  do {                                                                                     \
    if (LOADA) {                                                                           \
      _Pragma("unroll") for (int m_ = 0; m_ < 8; ++m_) aF[m_] = LDA_(m_, kb, buf);         \
    }                                                                                      \
    bF[0] = LDB_(2 * (nh) + 0, kb, buf);                                                   \
    bF[1] = LDB_(2 * (nh) + 1, kb, buf);                                                   \
    STMT_STAGE;                                                                            \
    if (DO_GATE) GATE6();                                                                  \
    BAR();                                                                                 \
    __builtin_amdgcn_s_setprio(1);                                                         \
    _Pragma("unroll") for (int m_ = 0; m_ < 8; ++m_) {                                     \
      acc[m_][2 * (nh) + 0] = __builtin_amdgcn_mfma_f32_16x16x32_bf16(                     \
          aF[m_], bF[0], acc[m_][2 * (nh) + 0], 0, 0, 0);                                  \
      acc[m_][2 * (nh) + 1] = __builtin_amdgcn_mfma_f32_16x16x32_bf16(                     \
          aF[m_], bF[1], acc[m_][2 * (nh) + 1], 0, 0, 0);                                  \
    }                                                                                      \
    __builtin_amdgcn_s_setprio(0);                                                         \
    BAR();                                                                                 \
  } while (0)

  // Prologue: stage tile0 fully + tile1 {A0,B0,A1}; gate so tile0 has landed.
  STAGE_A(0, 0, 0); STAGE_B(0, 0, 0); STAGE_A(0, 1, 0); STAGE_B(0, 1, 0);
  STAGE_A(1, 0, 1); STAGE_B(1, 0, 1); STAGE_A(1, 1, 1);
  GATE6();
  BAR();

  for (int i = 0; i < (NT >> 1); ++i) {
    int t1 = 2 * i + 1;
    int t2 = 2 * i + 2; if (t2 >= NT) t2 -= 2;  // tail: re-stage same-parity tile (identical data)
    int t3 = 2 * i + 3; if (t3 >= NT) t3 -= 2;
    // phases 0-3 compute tile 2i (buf0); 4-7 compute tile 2i+1 (buf1).
    // Each phase stages the half-tile whose LDS region was freed last phase.
    PHASE(0, 0, 0, 1, STAGE_B(t1, 1, 1), 0);
    PHASE(0, 0, 1, 0, STAGE_A(t2, 0, 0), 0);
    PHASE(0, 1, 0, 1, STAGE_B(t2, 0, 0), 0);
    PHASE(0, 1, 1, 0, STAGE_A(t2, 1, 0), 1);  // gate: tile 2i+1 fully landed
    PHASE(1, 0, 0, 1, STAGE_B(t2, 1, 0), 0);
    PHASE(1, 0, 1, 0, STAGE_A(t3, 0, 1), 0);
    PHASE(1, 1, 0, 1, STAGE_B(t3, 0, 1), 0);
    PHASE(1, 1, 1, 0, STAGE_A(t3, 1, 1), 1);  // gate: tile 2i+2 fully landed
  }

  // Epilogue: C/D frag layout col=lane&15, row=(lane>>4)*4+reg (m89/m91 verified).
  int col0 = tn * 256 + wn * 64;
  int row0 = tm * 256 + wm * 128;
  float bv[4];
#pragma unroll
  for (int n = 0; n < 4; ++n) bv[n] = bias[col0 + n * 16 + qr];
#pragma unroll
  for (int m = 0; m < 8; ++m) {
#pragma unroll
    for (int r = 0; r < 4; ++r) {
      float* cr = C + (size_t)(row0 + m * 16 + qg * 4 + r) * N;
#pragma unroll
      for (int n = 0; n < 4; ++n)
        cr[col0 + n * 16 + qr] = acc[m][n][r] + bv[n];
    }
  }
#undef PHASE
#undef STAGE_A
#undef STAGE_B
#undef LDA_
#undef LDB_
}

// ---------------- safety-net fp32 GEMM (only if fast-path preconditions fail) ----------------
__global__ __launch_bounds__(256) void naive_kernel(const float* __restrict__ x,
                                                    const float* __restrict__ W,
                                                    const float* __restrict__ b,
                                                    float* __restrict__ out,
                                                    int M, int N, int K) {
  long idx = (long)blockIdx.x * 256 + threadIdx.x;
  if (idx >= (long)M * N) return;
  int m = (int)(idx / N), n = (int)(idx % N);
  const float* xr = x + (size_t)m * K;
  const float* wr = W + (size_t)n * K;
  float s = 0.f;
  for (int k = 0; k < K; ++k) s += xr[k] * wr[k];
  out[idx] = s + b[n];
}

extern "C" void kernel_launch(void* const* d_in, const int* in_sizes, int n_in,
                              void* d_out, int out_size, void* d_ws, size_t ws_size,
                              hipStream_t stream) {
  const float* x = (const float*)d_in[0];  // [B,L,D] fp32
  const float* W = (const float*)d_in[1];  // [D,D] fp32 (out,in)
  const float* b = (const float*)d_in[2];  // [D] fp32
  float* out = (float*)d_out;

  int D = in_sizes[2];
  int M = in_sizes[0] / D;
  int N = D, K = D;

  int kdiv32 = K >> 5;
  size_t need = (size_t)(4u << 20) + (size_t)M * (size_t)K * sizeof(bf16_t);
  bool fast = (ws_size >= need) && (M % 256 == 0) && (N % 256 == 0) && (K % 128 == 0) &&
              (K >= 128) && ((kdiv32 & (kdiv32 - 1)) == 0) && (in_sizes[1] == N * K);

  if (fast) {
    int ksh = 0;
    while ((1 << (ksh + 1)) <= kdiv32) ++ksh;  // ksh = log2(K/32)

    bf16_t* Wb = (bf16_t*)d_ws;                        // frag-tiled W, 2 MB
    bf16_t* Xb = (bf16_t*)((char*)d_ws + (4u << 20));  // frag-tiled X, 64 MB

    long tW = (long)N * K / 8;
    hipLaunchKernelGGL(cvt_frag_kernel, dim3((unsigned)((tW + 255) / 256)), dim3(256), 0, stream,
                       W, Wb, K, ksh, tW);
    long tX = (long)M * K / 8;
    hipLaunchKernelGGL(cvt_frag_kernel, dim3((unsigned)((tX + 255) / 256)), dim3(256), 0, stream,
                       x, Xb, K, ksh, tX);

    int nwg = (M / 256) * (N / 256);
    hipLaunchKernelGGL(gemm8p_kernel, dim3(nwg), dim3(512), 0, stream,
                       Xb, Wb, b, out, M, N, K);
  } else {
    long total = (long)M * N;
    hipLaunchKernelGGL(naive_kernel, dim3((int)((total + 255) / 256)), dim3(256), 0, stream,
                       x, W, b, out, M, N, K);
  }
}

// Round 4
// 117.651 us; speedup vs baseline: 1.2055x; 1.0113x over previous
//
#include <hip/hip_runtime.h>
#include <hip/hip_bf16.h>
#include <stdint.h>

// FourierAttention = irfft(rfft(x)) @ W^T + b  ==  x @ W^T + b  (FFT roundtrip is identity).
// R4: 4-phase / 1-barrier schedule with the counted-vmcnt gate moved to BEFORE the
// barrier (R3 raced: gate-after-barrier only proves MY wave's loads landed; regions are
// staged cooperatively, so the guarantee must be established at the rendezvous point).

typedef __bf16 bf16_t;
typedef __bf16 bf16x8 __attribute__((ext_vector_type(8)));
typedef float f32x4 __attribute__((ext_vector_type(4)));

typedef __attribute__((address_space(1))) const void gvoid;
typedef __attribute__((address_space(3))) void svoid;

// ---------------- fp32 -> bf16 cvt into fragment-tiled layout ----------------
// subtile s = (r16_tile * (K/32) + k32_tile), 1KB each = 64 lanes x 16B;
// lane = qg*16 + qr holds  src[row = r16*16+qr][k = kb*32+qg*8 .. +7].
__global__ __launch_bounds__(256) void cvt_frag_kernel(const float* __restrict__ in,
                                                       bf16_t* __restrict__ out,
                                                       int K, int ksh, long total8) {
  long tid = (long)blockIdx.x * 256 + threadIdx.x;
  if (tid >= total8) return;
  int lane = (int)(tid & 63);
  long s = tid >> 6;
  int kb = (int)(s & ((1 << ksh) - 1));
  long m16 = s >> ksh;
  long row = m16 * 16 + (lane & 15);
  int k0 = kb * 32 + (lane >> 4) * 8;
  const float* p = in + row * (long)K + k0;
  f32x4 v0 = *(const f32x4*)p;
  f32x4 v1 = *(const f32x4*)(p + 4);
  bf16x8 o;
  o[0] = (bf16_t)v0[0]; o[1] = (bf16_t)v0[1]; o[2] = (bf16_t)v0[2]; o[3] = (bf16_t)v0[3];
  o[4] = (bf16_t)v1[0]; o[5] = (bf16_t)v1[1]; o[6] = (bf16_t)v1[2]; o[7] = (bf16_t)v1[3];
  *(bf16x8*)(out + tid * 8) = o;
}

// ---------------- 256x256 4-phase bf16 GEMM ----------------
// A (frag-tiled) [M/16][K/32][1KB], B (frag-tiled) [N/16][K/32][1KB].
// 512 thr = 8 waves (2M x 4N); wave tile 128x64; BK=64; LDS 128KB (2 bufs).
// Phase: 12 ds_read_b128 (this kb's frags) -> stage one kb-half (4 loads) ->
// 32 MFMA -> vmcnt(gate) -> s_barrier.  Steady state: 12 loads in flight, gate=8.
// Region read in phase p was staged in phase p-3; gate at end of p proves the
// p-2 stage landed for ALL waves once the barrier is crossed.

__device__ __forceinline__ void stage_half(const bf16_t* __restrict__ base, int tile16,
                                           int kdiv32, int t, int kb, int isB, int buf,
                                           bf16_t* lds, int wid, int lane8) {
#pragma unroll
  for (int r = 0; r < 2; ++r) {
    int s = r * 8 + wid;  // wave-uniform subtile index
    size_t gElem = ((((size_t)(tile16 + s)) * kdiv32 + (size_t)(t * 2 + kb)) << 9) + lane8;
    int dElem = buf * 32768 + isB * 16384 + (s * 2 + kb) * 512 + lane8;
    __builtin_amdgcn_global_load_lds((gvoid*)(base + gElem), (svoid*)(lds + dElem), 16, 0, 0);
  }
}

__global__ __launch_bounds__(512, 2) void gemm4p_kernel(
    const bf16_t* __restrict__ A, const bf16_t* __restrict__ B,
    const float* __restrict__ bias, float* __restrict__ C,
    int M, int N, int K) {
  __shared__ __align__(16) bf16_t lds[65536];  // 128 KB

  const int kdiv32 = K >> 5;
  const int NT = K >> 6;  // 64-wide K-tiles; host guarantees NT even, >= 2

  int nwg = gridDim.x;
  int bid = blockIdx.x;
  int wg = bid;
  if ((nwg & 7) == 0) wg = (bid & 7) * (nwg >> 3) + (bid >> 3);  // bijective XCD chunking
  int ntn = N >> 8;
  int tm = wg / ntn, tn = wg % ntn;

  int tid = threadIdx.x;
  int wid = tid >> 6, lane = tid & 63;
  int wm = wid >> 2, wn = wid & 3;  // 2 x 4 wave grid
  int qr = lane & 15, qg = lane >> 4;
  int lane8 = lane * 8;
  int wm8 = wm * 8;
  int wn4 = wn * 4;
  int tm16 = tm * 16, tn16 = tn * 16;

  f32x4 acc[8][4] = {};
  bf16x8 aF[8], bF[4];

#define STAGE_A(t, kb, buf) stage_half(A, tm16, kdiv32, (t), (kb), 0, (buf), lds, wid, lane8)
#define STAGE_B(t, kb, buf) stage_half(B, tn16, kdiv32, (t), (kb), 1, (buf), lds, wid, lane8)
#define LDA_(mm, kb, buf) (*(const bf16x8*)(lds + (buf)*32768 + ((wm8 + (mm)) * 2 + (kb)) * 512 + lane8))
#define LDB_(nn, kb, buf) (*(const bf16x8*)(lds + (buf)*32768 + 16384 + ((wn4 + (nn)) * 2 + (kb)) * 512 + lane8))

  // GN = vmcnt gate value at phase end (before barrier); DO_BAR lets the final
  // phase skip the gate+barrier entirely.
#define PHASE(buf, kb, ts, kbs, sbuf, GN, DO_STAGE, DO_BAR)                                \
  do {                                                                                     \
    _Pragma("unroll") for (int m_ = 0; m_ < 8; ++m_) aF[m_] = LDA_(m_, kb, buf);           \
    _Pragma("unroll") for (int n_ = 0; n_ < 4; ++n_) bF[n_] = LDB_(n_, kb, buf);           \
    if (DO_STAGE) { STAGE_A((ts), (kbs), (sbuf)); STAGE_B((ts), (kbs), (sbuf)); }          \
    __builtin_amdgcn_s_setprio(1);                                                         \
    _Pragma("unroll") for (int m_ = 0; m_ < 8; ++m_)                                       \
      _Pragma("unroll") for (int n_ = 0; n_ < 4; ++n_)                                     \
        acc[m_][n_] = __builtin_amdgcn_mfma_f32_16x16x32_bf16(aF[m_], bF[n_],              \
                                                              acc[m_][n_], 0, 0, 0);       \
    __builtin_amdgcn_s_setprio(0);                                                         \
    if (DO_BAR) {                                                                          \
      asm volatile("s_waitcnt vmcnt(" #GN ")" ::: "memory");                               \
      __builtin_amdgcn_s_barrier();                                                        \
    }                                                                                      \
  } while (0)

  // Prologue: stage t0-kb0, t0-kb1, t1-kb0 (12 loads); gate vmcnt(8) proves t0-kb0
  // landed for every wave once the barrier is crossed.
  STAGE_A(0, 0, 0); STAGE_B(0, 0, 0);
  STAGE_A(0, 1, 0); STAGE_B(0, 1, 0);
  STAGE_A(1, 0, 1); STAGE_B(1, 0, 1);
  asm volatile("s_waitcnt vmcnt(8)" ::: "memory");
  __builtin_amdgcn_s_barrier();

  // Steady state: P0 stages (2i+1)kb1->b1, P1:(2i+2)kb0->b0, P2:(2i+2)kb1->b0,
  // P3:(2i+3)kb0->b1; every gate is vmcnt(8) with 12 in flight.
  for (int i = 0; i < (NT >> 1) - 1; ++i) {
    int t1 = 2 * i + 1, t2 = 2 * i + 2, t3 = 2 * i + 3;
    PHASE(0, 0, t1, 1, 1, 8, 1, 1);
    PHASE(0, 1, t2, 0, 0, 8, 1, 1);
    PHASE(1, 0, t2, 1, 0, 8, 1, 1);
    PHASE(1, 1, t3, 0, 1, 8, 1, 1);
  }
  {  // final iteration: only (NT-1)-kb1 still needs staging; gates 8,4,0, none.
    int t1 = NT - 1;
    PHASE(0, 0, t1, 1, 1, 8, 1, 1);
    PHASE(0, 1, 0, 0, 0, 4, 0, 1);
    PHASE(1, 0, 0, 0, 0, 0, 0, 1);
    PHASE(1, 1, 0, 0, 0, 0, 0, 0);
  }

  // Epilogue: C/D frag layout col=lane&15, row=(lane>>4)*4+reg (m89/m91 verified).
  int col0 = tn * 256 + wn * 64;
  int row0 = tm * 256 + wm * 128;
  float bv[4];
#pragma unroll
  for (int n = 0; n < 4; ++n) bv[n] = bias[col0 + n * 16 + qr];
#pragma unroll
  for (int m = 0; m < 8; ++m) {
#pragma unroll
    for (int r = 0; r < 4; ++r) {
      float* cr = C + (size_t)(row0 + m * 16 + qg * 4 + r) * N;
#pragma unroll
      for (int n = 0; n < 4; ++n)
        cr[col0 + n * 16 + qr] = acc[m][n][r] + bv[n];
    }
  }
#undef PHASE
#undef STAGE_A
#undef STAGE_B
#undef LDA_
#undef LDB_
}

// ---------------- safety-net fp32 GEMM (only if fast-path preconditions fail) ----------------
__global__ __launch_bounds__(256) void naive_kernel(const float* __restrict__ x,
                                                    const float* __restrict__ W,
                                                    const float* __restrict__ b,
                                                    float* __restrict__ out,
                                                    int M, int N, int K) {
  long idx = (long)blockIdx.x * 256 + threadIdx.x;
  if (idx >= (long)M * N) return;
  int m = (int)(idx / N), n = (int)(idx % N);
  const float* xr = x + (size_t)m * K;
  const float* wr = W + (size_t)n * K;
  float s = 0.f;
  for (int k = 0; k < K; ++k) s += xr[k] * wr[k];
  out[idx] = s + b[n];
}

extern "C" void kernel_launch(void* const* d_in, const int* in_sizes, int n_in,
                              void* d_out, int out_size, void* d_ws, size_t ws_size,
                              hipStream_t stream) {
  const float* x = (const float*)d_in[0];  // [B,L,D] fp32
  const float* W = (const float*)d_in[1];  // [D,D] fp32 (out,in)
  const float* b = (const float*)d_in[2];  // [D] fp32
  float* out = (float*)d_out;

  int D = in_sizes[2];
  int M = in_sizes[0] / D;
  int N = D, K = D;

  int kdiv32 = K >> 5;
  size_t need = (size_t)(4u << 20) + (size_t)M * (size_t)K * sizeof(bf16_t);
  bool fast = (ws_size >= need) && (M % 256 == 0) && (N % 256 == 0) && (K % 128 == 0) &&
              (K >= 128) && ((kdiv32 & (kdiv32 - 1)) == 0) && (in_sizes[1] == N * K);

  if (fast) {
    int ksh = 0;
    while ((1 << (ksh + 1)) <= kdiv32) ++ksh;  // ksh = log2(K/32)

    bf16_t* Wb = (bf16_t*)d_ws;                        // frag-tiled W, 2 MB
    bf16_t* Xb = (bf16_t*)((char*)d_ws + (4u << 20));  // frag-tiled X, 64 MB

    long tW = (long)N * K / 8;
    hipLaunchKernelGGL(cvt_frag_kernel, dim3((unsigned)((tW + 255) / 256)), dim3(256), 0, stream,
                       W, Wb, K, ksh, tW);
    long tX = (long)M * K / 8;
    hipLaunchKernelGGL(cvt_frag_kernel, dim3((unsigned)((tX + 255) / 256)), dim3(256), 0, stream,
                       x, Xb, K, ksh, tX);

    int nwg = (M / 256) * (N / 256);
    hipLaunchKernelGGL(gemm4p_kernel, dim3(nwg), dim3(512), 0, stream,
                       Xb, Wb, b, out, M, N, K);
  } else {
    long total = (long)M * N;
    hipLaunchKernelGGL(naive_kernel, dim3((int)((total + 255) / 256)), dim3(256), 0, stream,
                       x, W, b, out, M, N, K);
  }
}

// Round 5
// 117.393 us; speedup vs baseline: 1.2082x; 1.0022x over previous
//
#include <hip/hip_runtime.h>
#include <hip/hip_bf16.h>
#include <stdint.h>

// FourierAttention = irfft(rfft(x)) @ W^T + b  ==  x @ W^T + b  (FFT roundtrip is identity).
// R5: one barrier per K-tile; stage whole next tile into the opposite buffer at tile
// start (no WAR inside a tile); kb1 ds_reads overlap kb0 MFMAs (compiler lgkmcnt
// scheduling). R4's convoy [reads-burst | MFMA-burst | barrier] serialized the LDS
// port (~2300 cyc/tile/CU) with the MFMA pipe (~2480 cyc/tile/SIMD); this overlaps them.

typedef __bf16 bf16_t;
typedef __bf16 bf16x8 __attribute__((ext_vector_type(8)));
typedef float f32x4 __attribute__((ext_vector_type(4)));

typedef __attribute__((address_space(1))) const void gvoid;
typedef __attribute__((address_space(3))) void svoid;

// ---------------- fp32 -> bf16 cvt into fragment-tiled layout ----------------
// subtile s = (r16_tile * (K/32) + k32_tile), 1KB each = 64 lanes x 16B;
// lane = qg*16 + qr holds  src[row = r16*16+qr][k = kb*32+qg*8 .. +7].
__global__ __launch_bounds__(256) void cvt_frag_kernel(const float* __restrict__ in,
                                                       bf16_t* __restrict__ out,
                                                       int K, int ksh, long total8) {
  long tid = (long)blockIdx.x * 256 + threadIdx.x;
  if (tid >= total8) return;
  int lane = (int)(tid & 63);
  long s = tid >> 6;
  int kb = (int)(s & ((1 << ksh) - 1));
  long m16 = s >> ksh;
  long row = m16 * 16 + (lane & 15);
  int k0 = kb * 32 + (lane >> 4) * 8;
  const float* p = in + row * (long)K + k0;
  f32x4 v0 = *(const f32x4*)p;
  f32x4 v1 = *(const f32x4*)(p + 4);
  bf16x8 o;
  o[0] = (bf16_t)v0[0]; o[1] = (bf16_t)v0[1]; o[2] = (bf16_t)v0[2]; o[3] = (bf16_t)v0[3];
  o[4] = (bf16_t)v1[0]; o[5] = (bf16_t)v1[1]; o[6] = (bf16_t)v1[2]; o[7] = (bf16_t)v1[3];
  *(bf16x8*)(out + tid * 8) = o;
}

// ---------------- 256x256 bf16 GEMM, 1 barrier / K-tile ----------------
// A (frag-tiled) [M/16][K/32][1KB], B (frag-tiled) [N/16][K/32][1KB].
// 512 thr = 8 waves (2M x 4N); wave tile 128x64; BK=64; LDS 128KB (2 tile-bufs).
// Tile loop: stage tile t+1 (8 gloads -> buf^1) ; frags+MFMA kb0 ; frags+MFMA kb1 ;
// vmcnt(0) ; barrier.  Stage loads age a whole tile (~2400 cyc) before the gate.

__device__ __forceinline__ void stage_half(const bf16_t* __restrict__ base, int tile16,
                                           int kdiv32, int t, int kb, int isB, int buf,
                                           bf16_t* lds, int wid, int lane8) {
#pragma unroll
  for (int r = 0; r < 2; ++r) {
    int s = r * 8 + wid;  // wave-uniform subtile index
    size_t gElem = ((((size_t)(tile16 + s)) * kdiv32 + (size_t)(t * 2 + kb)) << 9) + lane8;
    int dElem = buf * 32768 + isB * 16384 + (s * 2 + kb) * 512 + lane8;
    __builtin_amdgcn_global_load_lds((gvoid*)(base + gElem), (svoid*)(lds + dElem), 16, 0, 0);
  }
}

__global__ __launch_bounds__(512, 2) void gemm_tile_kernel(
    const bf16_t* __restrict__ A, const bf16_t* __restrict__ B,
    const float* __restrict__ bias, float* __restrict__ C,
    int M, int N, int K) {
  __shared__ __align__(16) bf16_t lds[65536];  // 128 KB

  const int kdiv32 = K >> 5;
  const int NT = K >> 6;  // 64-wide K-tiles; host guarantees NT >= 2

  int nwg = gridDim.x;
  int bid = blockIdx.x;
  int wg = bid;
  if ((nwg & 7) == 0) wg = (bid & 7) * (nwg >> 3) + (bid >> 3);  // bijective XCD chunking
  int ntn = N >> 8;
  int tm = wg / ntn, tn = wg % ntn;

  int tid = threadIdx.x;
  int wid = tid >> 6, lane = tid & 63;
  int wm = wid >> 2, wn = wid & 3;  // 2 x 4 wave grid
  int qr = lane & 15, qg = lane >> 4;
  int lane8 = lane * 8;
  int wm8 = wm * 8;
  int wn4 = wn * 4;
  int tm16 = tm * 16, tn16 = tn * 16;

  f32x4 acc[8][4] = {};

#define STAGE_A(t, kb, buf) stage_half(A, tm16, kdiv32, (t), (kb), 0, (buf), lds, wid, lane8)
#define STAGE_B(t, kb, buf) stage_half(B, tn16, kdiv32, (t), (kb), 1, (buf), lds, wid, lane8)

  // Prologue: stage tile 0 into buf 0; drain; rendezvous.
  STAGE_A(0, 0, 0); STAGE_B(0, 0, 0);
  STAGE_A(0, 1, 0); STAGE_B(0, 1, 0);
  asm volatile("s_waitcnt vmcnt(0)" ::: "memory");
  __builtin_amdgcn_s_barrier();

  for (int t = 0; t < NT; ++t) {
    int cur = t & 1;
    const bf16_t* __restrict__ ldsA = lds + cur * 32768;
    const bf16_t* __restrict__ ldsB = ldsA + 16384;

    if (t + 1 < NT) {  // stage next tile into the opposite buffer (no WAR inside tile)
      int nb = cur ^ 1;
      STAGE_A(t + 1, 0, nb); STAGE_B(t + 1, 0, nb);
      STAGE_A(t + 1, 1, nb); STAGE_B(t + 1, 1, nb);
    }

#pragma unroll
    for (int kb = 0; kb < 2; ++kb) {
      bf16x8 aF[8], bF[4];
#pragma unroll
      for (int m_ = 0; m_ < 8; ++m_)
        aF[m_] = *(const bf16x8*)(ldsA + ((wm8 + m_) * 2 + kb) * 512 + lane8);
#pragma unroll
      for (int n_ = 0; n_ < 4; ++n_)
        bF[n_] = *(const bf16x8*)(ldsB + ((wn4 + n_) * 2 + kb) * 512 + lane8);
      __builtin_amdgcn_s_setprio(1);
#pragma unroll
      for (int m_ = 0; m_ < 8; ++m_)
#pragma unroll
        for (int n_ = 0; n_ < 4; ++n_)
          acc[m_][n_] = __builtin_amdgcn_mfma_f32_16x16x32_bf16(aF[m_], bF[n_],
                                                                acc[m_][n_], 0, 0, 0);
      __builtin_amdgcn_s_setprio(0);
    }

    if (t + 1 < NT) {
      // Gate BEFORE the barrier: after the rendezvous, every wave's stage of
      // tile t+1 has landed. Loads are ~a full tile old here -> near-zero wait.
      asm volatile("s_waitcnt vmcnt(0)" ::: "memory");
      __builtin_amdgcn_s_barrier();
    }
  }

  // Epilogue: C/D frag layout col=lane&15, row=(lane>>4)*4+reg (m89/m91 verified).
  int col0 = tn * 256 + wn * 64;
  int row0 = tm * 256 + wm * 128;
  float bv[4];
#pragma unroll
  for (int n = 0; n < 4; ++n) bv[n] = bias[col0 + n * 16 + qr];
#pragma unroll
  for (int m = 0; m < 8; ++m) {
#pragma unroll
    for (int r = 0; r < 4; ++r) {
      float* cr = C + (size_t)(row0 + m * 16 + qg * 4 + r) * N;
#pragma unroll
      for (int n = 0; n < 4; ++n)
        cr[col0 + n * 16 + qr] = acc[m][n][r] + bv[n];
    }
  }
#undef STAGE_A
#undef STAGE_B
}

// ---------------- safety-net fp32 GEMM (only if fast-path preconditions fail) ----------------
__global__ __launch_bounds__(256) void naive_kernel(const float* __restrict__ x,
                                                    const float* __restrict__ W,
                                                    const float* __restrict__ b,
                                                    float* __restrict__ out,
                                                    int M, int N, int K) {
  long idx = (long)blockIdx.x * 256 + threadIdx.x;
  if (idx >= (long)M * N) return;
  int m = (int)(idx / N), n = (int)(idx % N);
  const float* xr = x + (size_t)m * K;
  const float* wr = W + (size_t)n * K;
  float s = 0.f;
  for (int k = 0; k < K; ++k) s += xr[k] * wr[k];
  out[idx] = s + b[n];
}

extern "C" void kernel_launch(void* const* d_in, const int* in_sizes, int n_in,
                              void* d_out, int out_size, void* d_ws, size_t ws_size,
                              hipStream_t stream) {
  const float* x = (const float*)d_in[0];  // [B,L,D] fp32
  const float* W = (const float*)d_in[1];  // [D,D] fp32 (out,in)
  const float* b = (const float*)d_in[2];  // [D] fp32
  float* out = (float*)d_out;

  int D = in_sizes[2];
  int M = in_sizes[0] / D;
  int N = D, K = D;

  int kdiv32 = K >> 5;
  size_t need = (size_t)(4u << 20) + (size_t)M * (size_t)K * sizeof(bf16_t);
  bool fast = (ws_size >= need) && (M % 256 == 0) && (N % 256 == 0) && (K % 128 == 0) &&
              (K >= 128) && ((kdiv32 & (kdiv32 - 1)) == 0) && (in_sizes[1] == N * K);

  if (fast) {
    int ksh = 0;
    while ((1 << (ksh + 1)) <= kdiv32) ++ksh;  // ksh = log2(K/32)

    bf16_t* Wb = (bf16_t*)d_ws;                        // frag-tiled W, 2 MB
    bf16_t* Xb = (bf16_t*)((char*)d_ws + (4u << 20));  // frag-tiled X, 64 MB

    long tW = (long)N * K / 8;
    hipLaunchKernelGGL(cvt_frag_kernel, dim3((unsigned)((tW + 255) / 256)), dim3(256), 0, stream,
                       W, Wb, K, ksh, tW);
    long tX = (long)M * K / 8;
    hipLaunchKernelGGL(cvt_frag_kernel, dim3((unsigned)((tX + 255) / 256)), dim3(256), 0, stream,
                       x, Xb, K, ksh, tX);

    int nwg = (M / 256) * (N / 256);
    hipLaunchKernelGGL(gemm_tile_kernel, dim3(nwg), dim3(512), 0, stream,
                       Xb, Wb, b, out, M, N, K);
  } else {
    long total = (long)M * N;
    hipLaunchKernelGGL(naive_kernel, dim3((int)((total + 255) / 256)), dim3(256), 0, stream,
                       x, W, b, out, M, N, K);
  }
}